// Round 10
// baseline (455.435 us; speedup 1.0000x reference)
//
#include <hip/hip_runtime.h>
#include <math.h>

#define PI_D 3.14159265358979323846

// N=10 images, E=64 ch, H=128, W=256, M=16 modes, L=4 layers
// act layout: [n][i 64][h 128][w 256] fp16

typedef _Float16 h8 __attribute__((ext_vector_type(8)));
typedef float f16v __attribute__((ext_vector_type(16)));

// Fast erf-gelu: Abramowitz-Stegun 7.1.26 (|erf err| <= 1.5e-7), branchless.
__device__ __forceinline__ float gelu_f(float v){
  float z  = v*0.70710678118654752440f;
  float az = fabsf(z);
  float t  = __builtin_amdgcn_rcpf(fmaf(0.3275911f, az, 1.0f));
  float p  = t*fmaf(t, fmaf(t, fmaf(t, fmaf(t, 1.061405429f, -1.453152027f),
                                    1.421413741f), -0.284496736f), 0.254829592f);
  float e  = __expf(-az*az);
  float er = copysignf(fmaf(-p, e, 1.0f), z);
  return 0.5f*v*(1.0f + er);
}

// Bx swizzle for k_combine. The extra (w>>4) bit makes fsw take 8 distinct values
// across the 16 w-subranges of the staging pack-write (was 4), spreading the
// ds_write_b32 transpose onto all 32 banks (2-way = free, was 4-way = 1.58x).
// MFMA b-fragment reads keep their 8-value spread. Pure XOR relabel: safe.
__device__ __forceinline__ int fsw_c(int w){ return (w ^ (w >> 3) ^ (w >> 4)) & 7; }

// ================= setup: correlations + boundary + tables + foldK =================
// blocks 0..319: full-plane correlations; 320..329: boundary; 330..377: tables; 378..379: foldK
__global__ __launch_bounds__(512) void k_setup(const float* __restrict__ sv, float* __restrict__ Rpart,
                                               float* __restrict__ Bnd,
                                               float* __restrict__ twFwH, float* __restrict__ twBwH,
                                               _Float16* __restrict__ Tspec, _Float16* __restrict__ TdftW,
                                               const float* __restrict__ smw, const float* __restrict__ upw,
                                               const float* __restrict__ upb, float* __restrict__ Keff){
  __shared__ float SH[3120];
  int bid = blockIdx.x;
  int tid = threadIdx.x;
  if (bid < 320){
    int band = bid & 31, n = bid >> 5;
    int u0 = band*4;
    for (int t = tid; t < 3120; t += 512){
      int ch = t / 1560; int rem = t - ch*1560; int rr = rem / 260; int ci = rem - rr*260;
      int row = u0 - 1 + rr, col = ci - 1;
      float v = 0.f;
      if (row >= 0 && row < 128 && col >= 0 && col < 256)
        v = sv[((size_t)(n*2+ch)*128 + row)*256 + col];
      SH[(ch*6+rr)*260 + ci] = v;
    }
    __syncthreads();

    int lane = tid & 63, wv = tid >> 6;
    int c  = (wv<4) ? (wv>>1) : ((wv<6) ? (wv-4) : 2);
    int c2 = (wv<4) ? (wv&1)  : ((wv<6) ? 2 : (wv-6));
    float acc[9];
    #pragma unroll
    for (int k=0;k<9;++k) acc[k]=0.f;

    for (int r=0;r<4;++r){
      int u = u0 + r, lu = r + 1;
      for (int cb=0;cb<4;++cb){
        int v = cb*64 + lane;
        float f = (c==2) ? 1.f : SH[(c*6+lu)*260 + 1+v];
        #pragma unroll
        for (int dr=-1;dr<=1;++dr){
          int ur = u + dr;
          float rko = (ur>=0 && ur<128) ? 1.f : 0.f;
          #pragma unroll
          for (int dc=-1;dc<=1;++dc){
            float g;
            if (c2==2){
              int vc = v + dc;
              g = rko * ((vc>=0 && vc<256) ? 1.f : 0.f);
            } else {
              g = SH[(c2*6+lu+dr)*260 + 1+v+dc];
            }
            acc[(dr+1)*3 + dc+1] += f*g;
          }
        }
      }
    }
    #pragma unroll
    for (int k=0;k<9;++k){
      float v = acc[k];
      for (int off=32; off; off>>=1) v += __shfl_xor(v, off);
      if (lane==0) Rpart[((size_t)(n*32+band)*8 + wv)*9 + k] = v;
    }
  } else if (bid < 330){
    int n = bid - 320;
    for (int t = tid; t < 3120; t += 512){
      int e = t/780; int rem = t - e*780; int ch = rem/260; int i = rem - ch*260;
      int idx = i - 1;
      int len = (e<2) ? 256 : 128;
      float v = 0.f;
      if (idx >= 0 && idx < len){
        if (ch==2) v = 1.f;
        else {
          int row = (e==0) ? 0 : (e==1) ? 127 : idx;
          int col = (e==2) ? 0 : (e==3) ? 255 : idx;
          v = sv[((size_t)(n*2+ch)*128 + row)*256 + col];
        }
      }
      SH[(e*3+ch)*260 + i] = v;
    }
    __syncthreads();
    if (tid < 108){
      int e = tid/27; int rem = tid - e*27; int pair = rem/3; int lag = rem%3 - 1;
      int c = pair/3, c2 = pair%3;
      int len = (e<2) ? 256 : 128;
      float a = 0.f;
      for (int i=0;i<len;++i) a += SH[(e*3+c)*260 + 1+i]*SH[(e*3+c2)*260 + 1+i+lag];
      Bnd[n*144 + tid] = a;
    } else if (tid < 144){
      int t = tid - 108; int corner = t/9; int pair = t - corner*9;
      int c = pair/3, c2 = pair%3;
      int e = (corner<2) ? 0 : 1;
      int idx = (corner&1) ? 255 : 0;
      Bnd[n*144 + tid] = SH[(e*3+c)*260 + 1+idx]*SH[(e*3+c2)*260 + 1+idx];
    }
  } else if (bid < 378){
    int id = (bid-330)*512 + tid;   // 0..24575
    if (id < 4096){
      int h = id >> 5, m = id & 31;
      int xm = (m < 16) ? m : (96 + m);
      double ang = -2.0*PI_D*(double)((xm*h) & 127)/128.0;
      twFwH[id*2]   = (float)cos(ang);
      twFwH[id*2+1] = (float)sin(ang);
    } else if (id < 8192){
      int j = id - 4096;
      int h = j >> 5, m = j & 31;          // h-major
      int xm = (m < 16) ? m : (96 + m);
      double ang = 2.0*PI_D*(double)((xm*h) & 127)/128.0;
      twBwH[j*2]   = (float)cos(ang);
      twBwH[j*2+1] = (float)sin(ang);
    } else if (id < 16384){
      int j = id - 8192;
      int w = j >> 5, kk = j & 31;
      int y = kk >> 1;
      double ang = 2.0*PI_D*(double)((w*y) & 255)/256.0;
      double v = (kk & 1) ? -sin(ang) : cos(ang);
      Tspec[j] = (_Float16)v;
    } else {
      int j = id - 16384;
      int y2 = j >> 8, w = j & 255;
      int y = y2 >> 1;
      double ang = -2.0*PI_D*(double)((w*y) & 255)/256.0;
      double v = (y2 & 1) ? sin(ang) : cos(ang);
      TdftW[j] = (_Float16)v;
    }
  } else {
    int id = (bid-378)*512 + tid;
    if (id >= 1024) return;
    int o = id >> 4, rs = (id >> 2) & 3, tap = id & 3;
    int r = rs >> 1, s = rs & 1, a = tap >> 1, b = tap & 1;
    int klo = (r==0) ? (a==0?0:1) : (a==0?0:2);
    int khi = (r==0) ? (a==0?0:2) : (a==0?1:2);
    int llo = (s==0) ? (b==0?0:1) : (b==0?0:2);
    int lhi = (s==0) ? (b==0?0:2) : (b==0?1:2);
    float a0=0.f, a1=0.f, ab=0.f;
    for (int i=0;i<64;++i){
      float t = 0.f;
      for (int kh=klo; kh<=khi; ++kh)
        for (int kw=llo; kw<=lhi; ++kw)
          t += smw[((size_t)o*64+i)*9 + kh*3+kw];
      a0 += t*upw[i*2];
      a1 += t*upw[i*2+1];
      ab += t*upb[i];
    }
    *(float4*)(Keff + o*64 + (rs*4+tap)*4) = make_float4(a0, a1, ab, 0.f);
  }
}

// ---------------- one-shot weight transpose: wr/wi -> Wt fp16 [l][blk][my][i][o](r,i) ----------------
__global__ __launch_bounds__(256) void k_transW(const float* __restrict__ wr, const float* __restrict__ wi,
                                                unsigned* __restrict__ Wt){
  __shared__ unsigned P[64*257];
  int lb = blockIdx.x;
  int i = lb & 63, blk = (lb>>6)&1, l = lb>>7;
  int tid = threadIdx.x;     // my = mm*16+y
  size_t sbase = (size_t)l*2097152 + (size_t)blk*1048576 + (size_t)i*16384 + tid;
  for (int o=0;o<64;++o){
    float a = wr[sbase + (size_t)o*256];
    float b = wi[sbase + (size_t)o*256];
    union { unsigned u; _Float16 h[2]; } pk;
    pk.h[0] = (_Float16)a; pk.h[1] = (_Float16)b;
    P[o*257 + tid] = pk.u;
  }
  __syncthreads();
  int o = tid & 63, g = tid >> 6;
  size_t dbase = (size_t)(l*2+blk)*1048576;
  for (int it=0; it<64; ++it){
    int my = g*64 + it;
    Wt[dbase + (size_t)my*4096 + i*64 + o] = P[o*257 + my];
  }
}

// ---- k_stats3: assemble Gram -> per-(n,o) mu/istd via quadratic form ----
__global__ __launch_bounds__(256) void k_stats3(const float* __restrict__ Rpart, const float* __restrict__ Bnd,
                                                const float* __restrict__ Keff, float* __restrict__ stats){
  __shared__ float R[9][9];
  __shared__ float BL[4][9][3];
  __shared__ float CR[4][9];
  __shared__ float M[4][12][12];
  int n = blockIdx.x, tid = threadIdx.x;

  if (tid < 72){
    int wv = tid/9, k = tid - (tid/9)*9;
    double s = 0.0;
    for (int b=0;b<32;++b) s += (double)Rpart[((size_t)(n*32+b)*8 + wv)*9 + k];
    int c  = (wv<4) ? (wv>>1) : ((wv<6) ? (wv-4) : 2);
    int c2 = (wv<4) ? (wv&1)  : ((wv<6) ? 2 : (wv-6));
    R[c*3+c2][k] = (float)s;
  } else if (tid < 81){
    int k = tid - 72; int dr = k/3 - 1, dc = k%3 - 1;
    R[8][k] = (float)((128 - (dr<0?-dr:dr)) * (256 - (dc<0?-dc:dc)));
  }
  if (tid < 108){
    int e = tid/27, rem = tid - (tid/27)*27;
    BL[e][rem/3][rem%3] = Bnd[n*144 + tid];
  } else if (tid < 144){
    int t = tid - 108;
    CR[t/9][t - (t/9)*9] = Bnd[n*144 + tid];
  }
  __syncthreads();

  for (int t = tid; t < 576; t += 256){
    int rs = t/144; int rem = t - rs*144; int i = rem/12, j = rem - (rem/12)*12;
    int ab = i/3,  c  = i - ab*3,  a  = ab>>1, b  = ab&1;
    int ab2 = j/3, c2 = j - ab2*3, a2 = ab2>>1, b2 = ab2&1;
    int r = rs>>1, s = rs&1;
    int dr = a2 - a, dc = b2 - b;
    int pair = c*3 + c2;
    float g = R[pair][(dr+1)*3 + (dc+1)];
    if (r==1 && a==1 && a2==1) g -= BL[0][pair][dc+1];
    if (r==0 && a==0 && a2==0) g -= BL[1][pair][dc+1];
    if (s==1 && b==1 && b2==1) g -= BL[2][pair][dr+1];
    if (s==0 && b==0 && b2==0) g -= BL[3][pair][dr+1];
    bool rowc = (a==a2) && ((r==1 && a==1) || (r==0 && a==0));
    bool colc = (b==b2) && ((s==1 && b==1) || (s==0 && b==0));
    if (rowc && colc){
      int corner = ((r==1)?0:2) + ((s==1)?0:1);
      g += CR[corner][pair];
    }
    M[rs][i][j] = g;
  }
  __syncthreads();

  if (tid < 64){
    int o = tid;
    double S1 = 0.0, S2 = 0.0;
    for (int rs=0; rs<4; ++rs){
      float w[12];
      #pragma unroll
      for (int ab=0; ab<4; ++ab){
        float4 kv = *(const float4*)(Keff + o*64 + (rs*4+ab)*4);
        w[ab*3+0] = kv.x; w[ab*3+1] = kv.y; w[ab*3+2] = kv.z;
      }
      #pragma unroll
      for (int i=0;i<12;++i){
        double ti = 0.0;
        #pragma unroll
        for (int j=0;j<12;++j) ti += (double)M[rs][i][j]*(double)w[j];
        S2 += (double)w[i]*ti;
      }
      #pragma unroll
      for (int ab=0; ab<4; ++ab)
        #pragma unroll
        for (int c=0;c<3;++c)
          S1 += (double)w[ab*3+c]*(double)M[rs][ab*3+c][ab*3+2];
    }
    double mu  = S1 / 131072.0;
    double var = S2 / 131072.0 - mu*mu;
    stats[(n*64+o)*2]   = (float)mu;
    stats[(n*64+o)*2+1] = (float)(1.0/sqrt(var + 1e-5));
  }
}

// ---------------- fused updim+conv (parity 0 only) + norm + gelu -> fp16 ----------------
__global__ __launch_bounds__(256) void k_convnorm(const float* __restrict__ sv,
                                                  const float* __restrict__ Keff,
                                                  const float* __restrict__ stats,
                                                  _Float16* __restrict__ act){
  __shared__ float SV[4*260];
  int bid = blockIdx.x;
  int p = bid & 127, n = bid >> 7;
  int tid = threadIdx.x;
  for (int t = tid; t < 1032; t += 256){
    int dr = t / 516;
    int rem = t - dr*516;
    int ch = rem / 258;
    int ci = rem - ch*258;
    int row = p - 1 + dr;
    int col = ci - 1;
    float v = 0.f;
    if (row >= 0 && col >= 0 && col < 256)
      v = sv[((size_t)(n*2+ch)*128 + row)*256 + col];
    SV[(dr*2+ch)*260 + ci] = v;
  }
  __syncthreads();

  int q = tid;
  float x0[4], x1[4], ib[4];
  float rowok0 = (p>0)?1.f:0.f;
  float colok0 = (q>0)?1.f:0.f;
  #pragma unroll
  for (int a=0;a<2;++a)
    #pragma unroll
    for (int b=0;b<2;++b){
      x0[a*2+b] = SV[(a*2+0)*260 + q + b];
      x1[a*2+b] = SV[(a*2+1)*260 + q + b];
      ib[a*2+b] = (a==0?rowok0:1.f) * (b==0?colok0:1.f);
    }

  for (int o=0; o<64; ++o){
    const float4* kp = (const float4*)(Keff + o*64);
    float y = 0.f;
    #pragma unroll
    for (int t=0;t<4;++t){
      float4 kv = kp[t];
      y += kv.x*x0[t] + kv.y*x1[t] + kv.z*ib[t];
    }
    float mu = stats[(n*64+o)*2], istd = stats[(n*64+o)*2+1];
    float v = (y - mu)*istd;
    act[((size_t)(n*64+o)*128 + p)*256 + q] = (_Float16)gelu_f(v);
  }
}

// ---------------- forward DFT along W via MFMA; Cy layout [n][y][h][e][2] ----------------
__global__ __launch_bounds__(256, 2) void k_dftW_mfma(const _Float16* __restrict__ act,
                                                      const _Float16* __restrict__ TdftW,
                                                      float* __restrict__ Cy){
  __shared__ _Float16 Ax[32768]; // act [a 128][w 256] chunk-swizzled
  __shared__ _Float16 Bt[8192];  // T   [y2 32][w 256] chunk-swizzled
  int tid = threadIdx.x;
  int hp = blockIdx.x & 63, n = blockIdx.x >> 6;
  int h0 = hp*2;

  {
    int a = tid >> 1;
    int ws = (tid & 1) * 128;
    int e = a & 63, ht = a >> 6;
    const _Float16* src = act + ((size_t)(n*64+e))*32768 + (size_t)(h0+ht)*256 + ws;
    #pragma unroll
    for (int k=0;k<16;++k){
      h8 v = *(const h8*)(src + k*8);
      int wq = (ws >> 3) + k;
      int chunk = wq ^ (a & 7);
      *(h8*)(Ax + a*256 + chunk*8) = v;
    }
  }
  {
    int y2 = tid & 31, ws = (tid >> 5) * 32;
    const _Float16* src = TdftW + y2*256 + ws;
    #pragma unroll
    for (int k=0;k<4;++k){
      h8 v = *(const h8*)(src + k*8);
      int wq = (ws >> 3) + k;
      int chunk = wq ^ (y2 & 7);
      *(h8*)(Bt + y2*256 + chunk*8) = v;
    }
  }
  __syncthreads();

  int lane = tid & 63;
  int l31 = lane & 31, l5 = lane >> 5;
  int mt = tid >> 6;
  int a = mt*32 + l31;

  f16v acc;
  #pragma unroll
  for (int j=0;j<16;++j) acc[j] = 0.f;
  #pragma unroll
  for (int ks=0;ks<16;++ks){
    int kb = ks*16 + l5*8;
    int cA = (kb>>3) ^ (a & 7);
    int cB = (kb>>3) ^ (l31 & 7);
    h8 af = *(const h8*)(Ax + a*256 + cA*8);   // B operand fragment (col=a)
    h8 bf = *(const h8*)(Bt + l31*256 + cB*8); // A operand fragment (row=y2)
    acc = __builtin_amdgcn_mfma_f32_32x32x16_f16(bf, af, acc, 0,0,0);
  }
  int e = a & 63, ht = a >> 6;
  #pragma unroll
  for (int j=0;j<16;j+=2){
    int y2 = (j&3) + 8*(j>>2) + 4*l5;   // even
    int yy = y2 >> 1;
    *(float2*)(Cy + (((size_t)(n*16+yy)*128 + h0+ht)*64 + e)*2) = make_float2(acc[j], acc[j+1]);
  }
}

// ---------------- spectral phase A+B: dftH (8 modes per block) + modemix ----------------
// grid 640 = mq*160 + (n*16+y); MS layout [n][y][m 32][o 64][c 2]
__global__ __launch_bounds__(256) void k_specAB(const float* __restrict__ Cy,
                                                const float* __restrict__ twF,
                                                const unsigned* __restrict__ Wt,
                                                float* __restrict__ MS, int l){
  __shared__ float CO[8*64*2]; // coeff [mm 8][i 64][2]
  int bid = blockIdx.x;
  int mq = bid / 160;
  int pid = bid - mq*160;
  int y = pid & 15, n = pid >> 4;
  int tid = threadIdx.x;
  int lane = tid & 63;
  int wv = __builtin_amdgcn_readfirstlane(tid >> 6);

  // ---- phase A: coeff[m][i] = sum_h twF[h][m] * Cy[h][i], 2 modes per wave ----
  {
    int m0 = mq*8 + wv*2;
    const float* cyb = Cy + (((size_t)(n*16+y)*128)*64 + lane)*2;
    const float* tf = twF + m0*2;
    float ar0=0.f, ai0=0.f, ar1=0.f, ai1=0.f;
    for (int h=0; h<128; ++h){
      float2 c = *(const float2*)(cyb + h*128);
      const float* tp = tf + h*64;        // wave-uniform -> s_load
      float t0r = tp[0], t0i = tp[1], t1r = tp[2], t1i = tp[3];
      ar0 += t0r*c.x - t0i*c.y; ai0 += t0r*c.y + t0i*c.x;
      ar1 += t1r*c.x - t1i*c.y; ai1 += t1r*c.y + t1i*c.x;
    }
    int mm = wv*2;
    *(float2*)(CO + (mm*64 + lane)*2)     = make_float2(ar0, ai0);
    *(float2*)(CO + ((mm+1)*64 + lane)*2) = make_float2(ar1, ai1);
  }
  __syncthreads();

  // ---- phase B: mo[m][o] = sum_i coeff[m][i] * W[my][i][o] (complex) ----
  {
    #pragma unroll
    for (int t2=0; t2<2; ++t2){
      int mm = wv*2 + t2;
      int m = mq*8 + mm;
      int blk = m >> 4, mloc = m & 15;
      int my = mloc*16 + y;
      const unsigned* wb = Wt + ((size_t)((l*2+blk)*256 + my))*4096 + lane;
      float mr = 0.f, mi = 0.f;
      for (int i=0;i<64;++i){
        float2 cc = *(const float2*)(CO + (mm*64 + i)*2);
        union { unsigned u; _Float16 h[2]; } pk;
        pk.u = wb[(size_t)i*64];
        float wr_f = (float)pk.h[0], wi_f = (float)pk.h[1];
        mr += cc.x*wr_f - cc.y*wi_f;
        mi += cc.x*wi_f + cc.y*wr_f;
      }
      *(float2*)(MS + (((size_t)(n*16+y)*32 + m)*64 + lane)*2) = make_float2(mr, mi);
    }
  }
}

// ---------------- spectral phase C: idftH, h-quarter per block ----------------
__global__ __launch_bounds__(256) void k_specC(const float* __restrict__ MS,
                                               const float* __restrict__ twB,
                                               float* __restrict__ G){
  __shared__ float SM[32*64*2]; // 16KB
  int bid = blockIdx.x;
  int hq = bid / 160;
  int pid = bid - hq*160;
  int y = pid & 15, n = pid >> 4;
  int tid = threadIdx.x;
  int lane = tid & 63;
  int wv = __builtin_amdgcn_readfirstlane(tid >> 6);

  {
    const float4* src = (const float4*)(MS + ((size_t)(n*16+y)*32)*128);
    float4* dst = (float4*)SM;
    #pragma unroll
    for (int t=0; t<4; ++t) dst[tid + t*256] = src[tid + t*256];
  }
  __syncthreads();

  float f = (y==0) ? (1.f/32768.f) : (2.f/32768.f);
  for (int k=0;k<8;++k){
    int h = hq*32 + wv*8 + k;
    const float* tb = twB + h*64;      // wave-uniform -> s_load
    float gr=0.f, gi=0.f;
    #pragma unroll
    for (int m=0;m<32;++m){
      float tr = tb[m*2], ti = tb[m*2+1];
      float2 mo2 = *(const float2*)(SM + (m*64+lane)*2);
      gr += tr*mo2.x - ti*mo2.y;
      gi += tr*mo2.y + ti*mo2.x;
    }
    size_t gb = (((size_t)(n*128+h)*16 + y)*2)*64 + lane;
    G[gb]      = gr*f;
    G[gb + 64] = gi*f;
  }
}

// ---------------- fused skip-GEMM + inverse DFT-W + gelu (+ next-layer DFT-W / downdim) ----------------
// 512 threads, 8 waves. flags: 1 = emit Cy for next layer; 2 = last layer (fused downdim -> out)
__global__ __launch_bounds__(512, 4) void k_combine_mfma(const _Float16* __restrict__ act_in,
                                                         const float* __restrict__ G,
                                                         const _Float16* __restrict__ Tspec,
                                                         const _Float16* __restrict__ TdftW,
                                                         const float* __restrict__ cw,
                                                         const float* __restrict__ cb,
                                                         const float* __restrict__ wd,
                                                         const float* __restrict__ bd,
                                                         _Float16* __restrict__ act_out,
                                                         float* __restrict__ Cy,
                                                         float* __restrict__ outp,
                                                         int flags){
  __shared__ __align__(16) _Float16 Lh[40960]; // 80 KB total
  _Float16* Bx = Lh;            // [w 256][k 128] chunk-swizzled (fsw_c), 64 KB
  _Float16* At = Lh + 32768;    // [o 64][k 128] chunk-swizzled (o&7), 16 KB
  int tid = threadIdx.x;
  int h = blockIdx.x & 127, n = blockIdx.x >> 7;

  { // act rows -> Bx transposed, pair-packed dword writes
    int rp = tid >> 4, sub = tid & 15;     // 32 row-pairs x 16 w-subranges
    int i0 = 2*rp;
    int wbase = sub*16;
    const _Float16* r0 = act_in + (size_t)(n*64+i0)*32768 + (size_t)h*256 + wbase;
    const _Float16* r1 = r0 + 32768;
    h8 A0 = *(const h8*)r0,     A1 = *(const h8*)(r0+8);
    h8 B0 = *(const h8*)r1,     B1 = *(const h8*)(r1+8);
    int cbs = rp >> 2;        // i0>>3
    int lo  = i0 & 7;         // half-offset within chunk (even)
    #pragma unroll
    for (int k=0;k<16;++k){
      union { _Float16 hh[2]; unsigned u; } pk;
      pk.hh[0] = (k<8) ? A0[k] : A1[k-8];
      pk.hh[1] = (k<8) ? B0[k] : B1[k-8];
      int w = wbase + k;
      int chunk = cbs ^ fsw_c(w);
      *(unsigned*)(Bx + w*128 + chunk*8 + lo) = pk.u;
    }
  }
  { // cw -> At (k 0..63)
    int o = tid >> 3, seg = (tid & 7)*8;
    float4 c0 = *(const float4*)(cw + o*64 + seg);
    float4 c1 = *(const float4*)(cw + o*64 + seg + 4);
    h8 v;
    v[0]=(_Float16)c0.x; v[1]=(_Float16)c0.y; v[2]=(_Float16)c0.z; v[3]=(_Float16)c0.w;
    v[4]=(_Float16)c1.x; v[5]=(_Float16)c1.y; v[6]=(_Float16)c1.z; v[7]=(_Float16)c1.w;
    int ch0 = (seg>>3) ^ (o & 7);
    *(h8*)(At + o*128 + ch0*8) = v;
  }
  { // G -> At (k 64..95)
    const float* gp = G + (size_t)(n*128 + h)*2048 + tid*4;
    float4 g = *(const float4*)gp;
    float gvx[4] = {g.x, g.y, g.z, g.w};
    int idx0 = tid*4;
    int yc = idx0 >> 6;          // uniform over the 4 values
    int o0 = idx0 & 63;
    int kk = 64 + yc;
    #pragma unroll
    for (int j=0;j<4;++j){
      int o = o0 + j;
      int chunk = (kk >> 3) ^ (o & 7);
      At[o*128 + chunk*8 + (kk & 7)] = (_Float16)gvx[j];
    }
  }
  { // Tspec -> Bx (k 64..95)
    int w = tid >> 1, half = tid & 1;
    const _Float16* tp = Tspec + w*32 + half*16;
    #pragma unroll
    for (int c=0;c<2;++c){
      h8 v = *(const h8*)(tp + c*8);
      int cc = half*2 + c;
      int chunk = (8 + cc) ^ fsw_c(w);
      *(h8*)(Bx + w*128 + chunk*8) = v;
    }
  }
  __syncthreads();

  int lane = tid & 63;
  int l31 = lane & 31, l5 = lane >> 5;
  int w0i = tid >> 6;            // 0..7
  int mt = w0i & 1, ng = w0i >> 1;  // o-half, w-quarter-pair
  int o_lane = mt*32 + l31;

  h8 af[6];
  #pragma unroll
  for (int ks=0;ks<6;++ks){
    int kb = ks*16 + l5*8;
    int chunk = (kb>>3) ^ (o_lane & 7);
    af[ks] = *(const h8*)(At + o_lane*128 + chunk*8);
  }
  float bias[16];
  #pragma unroll
  for (int j=0;j<16;++j) bias[j] = cb[mt*32 + (j&3) + 8*(j>>2) + 4*l5];

  f16v acc[2];
  #pragma unroll
  for (int q=0;q<2;++q)
    #pragma unroll
    for (int j=0;j<16;++j) acc[q][j] = bias[j];

  #pragma unroll
  for (int q=0;q<2;++q){
    int w = (ng*2+q)*32 + l31;
    const _Float16* bbase = Bx + w*128;
    int wf = fsw_c(w);
    #pragma unroll
    for (int ks=0;ks<6;++ks){
      int kb = ks*16 + l5*8;
      int chunk = (kb>>3) ^ wf;
      h8 bf = *(const h8*)(bbase + chunk*8);
      acc[q] = __builtin_amdgcn_mfma_f32_32x32x16_f16(af[ks], bf, acc[q], 0,0,0);
    }
  }

  // ---- epilogue: gelu (fp32), optional act store, then fused tail ----
  float gvv[32];
  #pragma unroll
  for (int q=0;q<2;++q)
    #pragma unroll
    for (int j=0;j<16;++j) gvv[q*16+j] = gelu_f(acc[q][j]);

  if (flags != 2){
    #pragma unroll
    for (int q=0;q<2;++q){
      int wcol = (ng*2+q)*32 + l31;
      #pragma unroll
      for (int j=0;j<16;++j){
        int o = mt*32 + (j&3) + 8*(j>>2) + 4*l5;
        act_out[(size_t)(n*64+o)*32768 + (size_t)h*256 + wcol] = (_Float16)gvv[q*16+j];
      }
    }
  }
  __syncthreads();   // all phase-1 LDS reads complete; regions reusable

  if (flags == 1){
    // ---- fused DFT-W for next layer: Cy[y2 32][o 64] = sum_w Td[y2][w] * g[o][w] ----
    _Float16* gL  = Lh;           // [o 64][w 256] chunk-swizzled (o&7), 32 KB
    _Float16* TdL = Lh + 16384;   // [y2 32][w 256] chunk-swizzled (y2&7), 16 KB
    #pragma unroll
    for (int q=0;q<2;++q){
      int wcol = (ng*2+q)*32 + l31;
      int wc3 = wcol >> 3, wc7 = wcol & 7;
      #pragma unroll
      for (int j=0;j<16;++j){
        int o = mt*32 + (j&3) + 8*(j>>2) + 4*l5;
        gL[o*256 + ((wc3 ^ (o & 7))*8) + wc7] = (_Float16)gvv[q*16+j];
      }
    }
    { // TdftW -> TdL
      int y2 = tid & 31, ws = (tid >> 5)*16;
      const _Float16* src = TdftW + y2*256 + ws;
      #pragma unroll
      for (int k=0;k<2;++k){
        h8 v = *(const h8*)(src + k*8);
        int chunk = ((ws>>3)+k) ^ (y2 & 7);
        *(h8*)(TdL + y2*256 + chunk*8) = v;
      }
    }
    __syncthreads();
    float* P = (float*)(Lh + 32768);   // 4 tiles [32 y2][32 o] fp32, 16 KB (At region)
    if (w0i < 4){
      int mt2 = w0i & 1, kh = w0i >> 1;
      int ocol = mt2*32 + l31;
      f16v acc2;
      #pragma unroll
      for (int j=0;j<16;++j) acc2[j] = 0.f;
      #pragma unroll
      for (int ks=0;ks<8;++ks){
        int kb = (kh*8+ks)*16 + l5*8;
        h8 af2 = *(const h8*)(gL  + ocol*256 + (((kb>>3) ^ (ocol & 7))*8));
        h8 bf2 = *(const h8*)(TdL + l31*256  + (((kb>>3) ^ (l31 & 7))*8));
        acc2 = __builtin_amdgcn_mfma_f32_32x32x16_f16(bf2, af2, acc2, 0,0,0);
      }
      #pragma unroll
      for (int j=0;j<16;++j){
        int y2 = (j&3) + 8*(j>>2) + 4*l5;
        P[w0i*1024 + y2*32 + l31] = acc2[j];
      }
    }
    __syncthreads();
    #pragma unroll
    for (int rep=0;rep<2;++rep){
      int t = rep*512 + tid;
      int yy = t >> 6, o = t & 63, mt2 = o >> 5, o31 = o & 31;
      float re = P[mt2*1024 + (2*yy)*32 + o31]   + P[(2+mt2)*1024 + (2*yy)*32 + o31];
      float im = P[mt2*1024 + (2*yy+1)*32 + o31] + P[(2+mt2)*1024 + (2*yy+1)*32 + o31];
      *(float2*)(Cy + (((size_t)(n*16+yy)*128 + h)*64 + o)*2) = make_float2(re, im);
    }
  } else {
    // ---- fused downdim: out[ch] = bd[ch] + sum_o wd[ch][o] * g[o][w] ----
    float p00=0.f,p01=0.f,p10=0.f,p11=0.f;   // [ch][q]
    #pragma unroll
    for (int j=0;j<16;++j){
      int o = mt*32 + (j&3) + 8*(j>>2) + 4*l5;
      float w0d = wd[o], w1d = wd[64+o];
      p00 += w0d*gvv[j];     p10 += w1d*gvv[j];
      p01 += w0d*gvv[16+j];  p11 += w1d*gvv[16+j];
    }
    p00 += __shfl_xor(p00,32); p10 += __shfl_xor(p10,32);
    p01 += __shfl_xor(p01,32); p11 += __shfl_xor(p11,32);
    float* red = (float*)(Lh + 32768);   // [wcol 256][mt 2][ch 2]
    if (l5 == 0){
      int wa = (ng*2+0)*32 + l31, wb2 = (ng*2+1)*32 + l31;
      red[wa*4  + mt*2 + 0] = p00; red[wa*4  + mt*2 + 1] = p10;
      red[wb2*4 + mt*2 + 0] = p01; red[wb2*4 + mt*2 + 1] = p11;
    }
    __syncthreads();
    {
      int ch = tid >> 8, wcol = tid & 255;
      float v = red[wcol*4 + ch] + red[wcol*4 + 2 + ch] + bd[ch];
      outp[(size_t)n*65536 + (size_t)ch*32768 + (size_t)h*256 + wcol] = v;
    }
  }
}

extern "C" void kernel_launch(void* const* d_in, const int* in_sizes, int n_in,
                              void* d_out, int out_size, void* d_ws, size_t ws_size,
                              hipStream_t stream) {
  const float* sv  = (const float*)d_in[0];
  const float* upw = (const float*)d_in[1];
  const float* upb = (const float*)d_in[2];
  const float* smw = (const float*)d_in[3];
  const float* smb = (const float*)d_in[4];
  const float* fwr = (const float*)d_in[5];
  const float* fwi = (const float*)d_in[6];
  const float* fcw = (const float*)d_in[7];
  const float* fcb = (const float*)d_in[8];
  const float* ddw = (const float*)d_in[9];
  const float* ddb = (const float*)d_in[10];
  float* out = (float*)d_out;
  (void)smb; // spatially uniform per (n,o); cancelled exactly by instance-norm mean subtraction

  float* W = (float*)d_ws;
  _Float16* actA = (_Float16*)W;                    // 20971520 halves
  _Float16* actB = (_Float16*)(W + 10485760);       // 20971520 halves
  float* Cy    = W + 20971520;                      // 2621440  [n][y][h][e][2]
  float* G     = W + 23592960;                      // 2621440  [n][h][y][c][o]
  float* part  = W + 26214400;                      // Rpart/Bnd/MS
  float* stats = W + 28180480;                      // 1280
  float* Keff  = W + 28181760;                      // 4096
  float* twFwH = W + 28185856;                      // 8192
  float* twBwH = W + 28194048;                      // 8192
  _Float16* Tspec = (_Float16*)(W + 28202240);      // 8192 halves
  _Float16* TdftW = (_Float16*)(W + 28206336);      // 8192 halves
  unsigned* Wt   = (unsigned*)(W + 28210432);       // 8388608 u32 (33.5 MB)

  float* Rpart = part;          // 23040 floats: [n 10][band 32][pair 8][lag 9]
  float* Bnd   = part + 30000;  // 1440 floats:  [n 10][144]
  float* MS    = part + 65536;  // 655360 floats: [n 10][y 16][m 32][o 64][c 2]

  k_setup<<<380,512,0,stream>>>(sv, Rpart, Bnd, twFwH, twBwH, Tspec, TdftW, smw, upw, upb, Keff);
  k_transW<<<512,256,0,stream>>>(fwr, fwi, Wt);
  k_stats3<<<10,256,0,stream>>>(Rpart, Bnd, Keff, stats);
  k_convnorm<<<1280,256,0,stream>>>(sv, Keff, stats, actA);
  k_dftW_mfma<<<640,256,0,stream>>>(actA, TdftW, Cy);

  _Float16* xa = actA; _Float16* xb = actB;
  for (int l=0;l<4;++l){
    k_specAB<<<640,256,0,stream>>>(Cy, twFwH, Wt, MS, l);
    k_specC<<<640,256,0,stream>>>(MS, twBwH, G);
    k_combine_mfma<<<1280,512,0,stream>>>(xa, G, Tspec, TdftW,
                                          fcw + (size_t)l*4096, fcb + (size_t)l*64,
                                          ddw, ddb, xb, Cy, out, (l<3)?1:2);
    _Float16* t = xa; xa = xb; xb = t;
  }
}

// Round 11
// 450.665 us; speedup vs baseline: 1.0106x; 1.0106x over previous
//
#include <hip/hip_runtime.h>
#include <math.h>

#define PI_D 3.14159265358979323846

// N=10 images, E=64 ch, H=128, W=256, M=16 modes, L=4 layers
// act layout: [n][i 64][h 128][w 256] fp16

typedef _Float16 h8 __attribute__((ext_vector_type(8)));
typedef float f16v __attribute__((ext_vector_type(16)));

// Fast erf-gelu: Abramowitz-Stegun 7.1.26 (|erf err| <= 1.5e-7), branchless.
__device__ __forceinline__ float gelu_f(float v){
  float z  = v*0.70710678118654752440f;
  float az = fabsf(z);
  float t  = __builtin_amdgcn_rcpf(fmaf(0.3275911f, az, 1.0f));
  float p  = t*fmaf(t, fmaf(t, fmaf(t, fmaf(t, 1.061405429f, -1.453152027f),
                                    1.421413741f), -0.284496736f), 0.254829592f);
  float e  = __expf(-az*az);
  float er = copysignf(fmaf(-p, e, 1.0f), z);
  return 0.5f*v*(1.0f + er);
}

// Bx swizzle for k_combine. The (w>>4) bit makes fsw take 8 distinct values across
// the 16 w-subranges of the staging pack-write (was 4), spreading the ds_write_b32
// transpose onto all 32 banks (2-way = free, was 4-way = 1.58x). MFMA b-fragment
// reads keep their 8-value spread. Pure XOR relabel applied at all 3 sites: safe.
__device__ __forceinline__ int fsw_c(int w){ return (w ^ (w >> 3) ^ (w >> 4)) & 7; }

// ---------------- tables + foldK merged ----------------
// blocks 0..95: tables; blocks 96..99: foldK
__global__ __launch_bounds__(256) void k_tables_fold(float* __restrict__ twFwH, float* __restrict__ twBwH,
                                                     _Float16* __restrict__ Tspec, _Float16* __restrict__ TdftW,
                                                     const float* __restrict__ smw, const float* __restrict__ upw,
                                                     const float* __restrict__ upb, float* __restrict__ Keff){
  int bid = blockIdx.x;
  if (bid < 96){
    int id = bid*256 + threadIdx.x;
    if (id < 4096){
      int h = id >> 5, m = id & 31;
      int xm = (m < 16) ? m : (96 + m);
      double ang = -2.0*PI_D*(double)((xm*h) & 127)/128.0;
      twFwH[id*2]   = (float)cos(ang);
      twFwH[id*2+1] = (float)sin(ang);
    } else if (id < 8192){
      int j = id - 4096;
      int h = j >> 5, m = j & 31;          // h-major
      int xm = (m < 16) ? m : (96 + m);
      double ang = 2.0*PI_D*(double)((xm*h) & 127)/128.0;
      twBwH[j*2]   = (float)cos(ang);
      twBwH[j*2+1] = (float)sin(ang);
    } else if (id < 16384){
      int j = id - 8192;
      int w = j >> 5, kk = j & 31;
      int y = kk >> 1;
      double ang = 2.0*PI_D*(double)((w*y) & 255)/256.0;
      double v = (kk & 1) ? -sin(ang) : cos(ang);
      Tspec[j] = (_Float16)v;
    } else if (id < 24576){
      int j = id - 16384;
      int y2 = j >> 8, w = j & 255;
      int y = y2 >> 1;
      double ang = -2.0*PI_D*(double)((w*y) & 255)/256.0;
      double v = (y2 & 1) ? sin(ang) : cos(ang);
      TdftW[j] = (_Float16)v;
    }
  } else {
    int id = (bid-96)*256 + threadIdx.x;
    if (id >= 1024) return;
    int o = id >> 4, rs = (id >> 2) & 3, tap = id & 3;
    int r = rs >> 1, s = rs & 1, a = tap >> 1, b = tap & 1;
    int klo = (r==0) ? (a==0?0:1) : (a==0?0:2);
    int khi = (r==0) ? (a==0?0:2) : (a==0?1:2);
    int llo = (s==0) ? (b==0?0:1) : (b==0?0:2);
    int lhi = (s==0) ? (b==0?0:2) : (b==0?1:2);
    float a0=0.f, a1=0.f, ab=0.f;
    for (int i=0;i<64;++i){
      float t = 0.f;
      for (int kh=klo; kh<=khi; ++kh)
        for (int kw=llo; kw<=lhi; ++kw)
          t += smw[((size_t)o*64+i)*9 + kh*3+kw];
      a0 += t*upw[i*2];
      a1 += t*upw[i*2+1];
      ab += t*upb[i];
    }
    *(float4*)(Keff + o*64 + (rs*4+tap)*4) = make_float4(a0, a1, ab, 0.f);
  }
}

// ---------------- one-shot weight transpose: wr/wi -> Wt fp16 [l][blk][my][i][o](r,i) ----------------
__global__ __launch_bounds__(256) void k_transW(const float* __restrict__ wr, const float* __restrict__ wi,
                                                unsigned* __restrict__ Wt){
  __shared__ unsigned P[64*257];
  int lb = blockIdx.x;
  int i = lb & 63, blk = (lb>>6)&1, l = lb>>7;
  int tid = threadIdx.x;     // my = mm*16+y
  size_t sbase = (size_t)l*2097152 + (size_t)blk*1048576 + (size_t)i*16384 + tid;
  for (int o=0;o<64;++o){
    float a = wr[sbase + (size_t)o*256];
    float b = wi[sbase + (size_t)o*256];
    union { unsigned u; _Float16 h[2]; } pk;
    pk.h[0] = (_Float16)a; pk.h[1] = (_Float16)b;
    P[o*257 + tid] = pk.u;
  }
  __syncthreads();
  int o = tid & 63, g = tid >> 6;
  size_t dbase = (size_t)(l*2+blk)*1048576;
  for (int it=0; it<64; ++it){
    int my = g*64 + it;
    Wt[dbase + (size_t)my*4096 + i*64 + o] = P[o*257 + my];
  }
}

// ================= closed-form instance-norm statistics =================
// ---- k_corrbnd: blocks 0..319 full-plane correlations; blocks 320..329 boundary ----
__global__ __launch_bounds__(512) void k_corrbnd(const float* __restrict__ sv, float* __restrict__ Rpart,
                                                 float* __restrict__ Bnd){
  __shared__ float SH[3120];
  int bid = blockIdx.x;
  int tid = threadIdx.x;
  if (bid < 320){
    int band = bid & 31, n = bid >> 5;
    int u0 = band*4;
    for (int t = tid; t < 3120; t += 512){
      int ch = t / 1560; int rem = t - ch*1560; int rr = rem / 260; int ci = rem - rr*260;
      int row = u0 - 1 + rr, col = ci - 1;
      float v = 0.f;
      if (row >= 0 && row < 128 && col >= 0 && col < 256)
        v = sv[((size_t)(n*2+ch)*128 + row)*256 + col];
      SH[(ch*6+rr)*260 + ci] = v;
    }
    __syncthreads();

    int lane = tid & 63, wv = tid >> 6;
    int c  = (wv<4) ? (wv>>1) : ((wv<6) ? (wv-4) : 2);
    int c2 = (wv<4) ? (wv&1)  : ((wv<6) ? 2 : (wv-6));
    float acc[9];
    #pragma unroll
    for (int k=0;k<9;++k) acc[k]=0.f;

    for (int r=0;r<4;++r){
      int u = u0 + r, lu = r + 1;
      for (int cb=0;cb<4;++cb){
        int v = cb*64 + lane;
        float f = (c==2) ? 1.f : SH[(c*6+lu)*260 + 1+v];
        #pragma unroll
        for (int dr=-1;dr<=1;++dr){
          int ur = u + dr;
          float rko = (ur>=0 && ur<128) ? 1.f : 0.f;
          #pragma unroll
          for (int dc=-1;dc<=1;++dc){
            float g;
            if (c2==2){
              int vc = v + dc;
              g = rko * ((vc>=0 && vc<256) ? 1.f : 0.f);
            } else {
              g = SH[(c2*6+lu+dr)*260 + 1+v+dc];
            }
            acc[(dr+1)*3 + dc+1] += f*g;
          }
        }
      }
    }
    #pragma unroll
    for (int k=0;k<9;++k){
      float v = acc[k];
      for (int off=32; off; off>>=1) v += __shfl_xor(v, off);
      if (lane==0) Rpart[((size_t)(n*32+band)*8 + wv)*9 + k] = v;
    }
  } else {
    int n = bid - 320;
    for (int t = tid; t < 3120; t += 512){
      int e = t/780; int rem = t - e*780; int ch = rem/260; int i = rem - ch*260;
      int idx = i - 1;
      int len = (e<2) ? 256 : 128;
      float v = 0.f;
      if (idx >= 0 && idx < len){
        if (ch==2) v = 1.f;
        else {
          int row = (e==0) ? 0 : (e==1) ? 127 : idx;
          int col = (e==2) ? 0 : (e==3) ? 255 : idx;
          v = sv[((size_t)(n*2+ch)*128 + row)*256 + col];
        }
      }
      SH[(e*3+ch)*260 + i] = v;
    }
    __syncthreads();
    if (tid < 108){
      int e = tid/27; int rem = tid - e*27; int pair = rem/3; int lag = rem%3 - 1;
      int c = pair/3, c2 = pair%3;
      int len = (e<2) ? 256 : 128;
      float a = 0.f;
      for (int i=0;i<len;++i) a += SH[(e*3+c)*260 + 1+i]*SH[(e*3+c2)*260 + 1+i+lag];
      Bnd[n*144 + tid] = a;
    } else if (tid < 144){
      int t = tid - 108; int corner = t/9; int pair = t - corner*9;
      int c = pair/3, c2 = pair%3;
      int e = (corner<2) ? 0 : 1;
      int idx = (corner&1) ? 255 : 0;
      Bnd[n*144 + tid] = SH[(e*3+c)*260 + 1+idx]*SH[(e*3+c2)*260 + 1+idx];
    }
  }
}

// ---- k_stats3: assemble Gram -> per-(n,o) mu/istd via quadratic form ----
__global__ __launch_bounds__(256) void k_stats3(const float* __restrict__ Rpart, const float* __restrict__ Bnd,
                                                const float* __restrict__ Keff, float* __restrict__ stats){
  __shared__ float R[9][9];
  __shared__ float BL[4][9][3];
  __shared__ float CR[4][9];
  __shared__ float M[4][12][12];
  int n = blockIdx.x, tid = threadIdx.x;

  if (tid < 72){
    int wv = tid/9, k = tid - (tid/9)*9;
    double s = 0.0;
    for (int b=0;b<32;++b) s += (double)Rpart[((size_t)(n*32+b)*8 + wv)*9 + k];
    int c  = (wv<4) ? (wv>>1) : ((wv<6) ? (wv-4) : 2);
    int c2 = (wv<4) ? (wv&1)  : ((wv<6) ? 2 : (wv-6));
    R[c*3+c2][k] = (float)s;
  } else if (tid < 81){
    int k = tid - 72; int dr = k/3 - 1, dc = k%3 - 1;
    R[8][k] = (float)((128 - (dr<0?-dr:dr)) * (256 - (dc<0?-dc:dc)));
  }
  if (tid < 108){
    int e = tid/27, rem = tid - (tid/27)*27;
    BL[e][rem/3][rem%3] = Bnd[n*144 + tid];
  } else if (tid < 144){
    int t = tid - 108;
    CR[t/9][t - (t/9)*9] = Bnd[n*144 + tid];
  }
  __syncthreads();

  for (int t = tid; t < 576; t += 256){
    int rs = t/144; int rem = t - rs*144; int i = rem/12, j = rem - (rem/12)*12;
    int ab = i/3,  c  = i - ab*3,  a  = ab>>1, b  = ab&1;
    int ab2 = j/3, c2 = j - ab2*3, a2 = ab2>>1, b2 = ab2&1;
    int r = rs>>1, s = rs&1;
    int dr = a2 - a, dc = b2 - b;
    int pair = c*3 + c2;
    float g = R[pair][(dr+1)*3 + (dc+1)];
    if (r==1 && a==1 && a2==1) g -= BL[0][pair][dc+1];
    if (r==0 && a==0 && a2==0) g -= BL[1][pair][dc+1];
    if (s==1 && b==1 && b2==1) g -= BL[2][pair][dr+1];
    if (s==0 && b==0 && b2==0) g -= BL[3][pair][dr+1];
    bool rowc = (a==a2) && ((r==1 && a==1) || (r==0 && a==0));
    bool colc = (b==b2) && ((s==1 && b==1) || (s==0 && b==0));
    if (rowc && colc){
      int corner = ((r==1)?0:2) + ((s==1)?0:1);
      g += CR[corner][pair];
    }
    M[rs][i][j] = g;
  }
  __syncthreads();

  if (tid < 64){
    int o = tid;
    double S1 = 0.0, S2 = 0.0;
    for (int rs=0; rs<4; ++rs){
      float w[12];
      #pragma unroll
      for (int ab=0; ab<4; ++ab){
        float4 kv = *(const float4*)(Keff + o*64 + (rs*4+ab)*4);
        w[ab*3+0] = kv.x; w[ab*3+1] = kv.y; w[ab*3+2] = kv.z;
      }
      #pragma unroll
      for (int i=0;i<12;++i){
        double ti = 0.0;
        #pragma unroll
        for (int j=0;j<12;++j) ti += (double)M[rs][i][j]*(double)w[j];
        S2 += (double)w[i]*ti;
      }
      #pragma unroll
      for (int ab=0; ab<4; ++ab)
        #pragma unroll
        for (int c=0;c<3;++c)
          S1 += (double)w[ab*3+c]*(double)M[rs][ab*3+c][ab*3+2];
    }
    double mu  = S1 / 131072.0;
    double var = S2 / 131072.0 - mu*mu;
    stats[(n*64+o)*2]   = (float)mu;
    stats[(n*64+o)*2+1] = (float)(1.0/sqrt(var + 1e-5));
  }
}

// ---------------- fused updim+conv (parity 0 only) + norm + gelu -> fp16 ----------------
__global__ __launch_bounds__(256) void k_convnorm(const float* __restrict__ sv,
                                                  const float* __restrict__ Keff,
                                                  const float* __restrict__ stats,
                                                  _Float16* __restrict__ act){
  __shared__ float SV[4*260];
  int bid = blockIdx.x;
  int p = bid & 127, n = bid >> 7;
  int tid = threadIdx.x;
  for (int t = tid; t < 1032; t += 256){
    int dr = t / 516;
    int rem = t - dr*516;
    int ch = rem / 258;
    int ci = rem - ch*258;
    int row = p - 1 + dr;
    int col = ci - 1;
    float v = 0.f;
    if (row >= 0 && col >= 0 && col < 256)
      v = sv[((size_t)(n*2+ch)*128 + row)*256 + col];
    SV[(dr*2+ch)*260 + ci] = v;
  }
  __syncthreads();

  int q = tid;
  float x0[4], x1[4], ib[4];
  float rowok0 = (p>0)?1.f:0.f;
  float colok0 = (q>0)?1.f:0.f;
  #pragma unroll
  for (int a=0;a<2;++a)
    #pragma unroll
    for (int b=0;b<2;++b){
      x0[a*2+b] = SV[(a*2+0)*260 + q + b];
      x1[a*2+b] = SV[(a*2+1)*260 + q + b];
      ib[a*2+b] = (a==0?rowok0:1.f) * (b==0?colok0:1.f);
    }

  for (int o=0; o<64; ++o){
    const float4* kp = (const float4*)(Keff + o*64);
    float y = 0.f;
    #pragma unroll
    for (int t=0;t<4;++t){
      float4 kv = kp[t];
      y += kv.x*x0[t] + kv.y*x1[t] + kv.z*ib[t];
    }
    float mu = stats[(n*64+o)*2], istd = stats[(n*64+o)*2+1];
    float v = (y - mu)*istd;
    act[((size_t)(n*64+o)*128 + p)*256 + q] = (_Float16)gelu_f(v);
  }
}

// ---------------- forward DFT along W via MFMA; Cy layout [n][y][h][e][2] ----------------
__global__ __launch_bounds__(256, 2) void k_dftW_mfma(const _Float16* __restrict__ act,
                                                      const _Float16* __restrict__ TdftW,
                                                      float* __restrict__ Cy){
  __shared__ _Float16 Ax[32768]; // act [a 128][w 256] chunk-swizzled
  __shared__ _Float16 Bt[8192];  // T   [y2 32][w 256] chunk-swizzled
  int tid = threadIdx.x;
  int hp = blockIdx.x & 63, n = blockIdx.x >> 6;
  int h0 = hp*2;

  {
    int a = tid >> 1;
    int ws = (tid & 1) * 128;
    int e = a & 63, ht = a >> 6;
    const _Float16* src = act + ((size_t)(n*64+e))*32768 + (size_t)(h0+ht)*256 + ws;
    #pragma unroll
    for (int k=0;k<16;++k){
      h8 v = *(const h8*)(src + k*8);
      int wq = (ws >> 3) + k;
      int chunk = wq ^ (a & 7);
      *(h8*)(Ax + a*256 + chunk*8) = v;
    }
  }
  {
    int y2 = tid & 31, ws = (tid >> 5) * 32;
    const _Float16* src = TdftW + y2*256 + ws;
    #pragma unroll
    for (int k=0;k<4;++k){
      h8 v = *(const h8*)(src + k*8);
      int wq = (ws >> 3) + k;
      int chunk = wq ^ (y2 & 7);
      *(h8*)(Bt + y2*256 + chunk*8) = v;
    }
  }
  __syncthreads();

  int lane = tid & 63;
  int l31 = lane & 31, l5 = lane >> 5;
  int mt = tid >> 6;
  int a = mt*32 + l31;

  f16v acc;
  #pragma unroll
  for (int j=0;j<16;++j) acc[j] = 0.f;
  #pragma unroll
  for (int ks=0;ks<16;++ks){
    int kb = ks*16 + l5*8;
    int cA = (kb>>3) ^ (a & 7);
    int cB = (kb>>3) ^ (l31 & 7);
    h8 af = *(const h8*)(Ax + a*256 + cA*8);   // B operand fragment (col=a)
    h8 bf = *(const h8*)(Bt + l31*256 + cB*8); // A operand fragment (row=y2)
    acc = __builtin_amdgcn_mfma_f32_32x32x16_f16(bf, af, acc, 0,0,0);
  }
  int e = a & 63, ht = a >> 6;
  #pragma unroll
  for (int j=0;j<16;j+=2){
    int y2 = (j&3) + 8*(j>>2) + 4*l5;   // even
    int yy = y2 >> 1;
    *(float2*)(Cy + (((size_t)(n*16+yy)*128 + h0+ht)*64 + e)*2) = make_float2(acc[j], acc[j+1]);
  }
}

// ---------------- spectral phase A+B: dftH (8 modes per block) + modemix ----------------
// grid 640 = mq*160 + (n*16+y); MS layout [n][y][m 32][o 64][c 2]
__global__ __launch_bounds__(256) void k_specAB(const float* __restrict__ Cy,
                                                const float* __restrict__ twF,
                                                const unsigned* __restrict__ Wt,
                                                float* __restrict__ MS, int l){
  __shared__ float CO[8*64*2]; // coeff [mm 8][i 64][2]
  int bid = blockIdx.x;
  int mq = bid / 160;
  int pid = bid - mq*160;
  int y = pid & 15, n = pid >> 4;
  int tid = threadIdx.x;
  int lane = tid & 63;
  int wv = __builtin_amdgcn_readfirstlane(tid >> 6);

  // ---- phase A: coeff[m][i] = sum_h twF[h][m] * Cy[h][i], 2 modes per wave ----
  {
    int m0 = mq*8 + wv*2;
    const float* cyb = Cy + (((size_t)(n*16+y)*128)*64 + lane)*2;
    const float* tf = twF + m0*2;
    float ar0=0.f, ai0=0.f, ar1=0.f, ai1=0.f;
    for (int h=0; h<128; ++h){
      float2 c = *(const float2*)(cyb + h*128);
      const float* tp = tf + h*64;        // wave-uniform -> s_load
      float t0r = tp[0], t0i = tp[1], t1r = tp[2], t1i = tp[3];
      ar0 += t0r*c.x - t0i*c.y; ai0 += t0r*c.y + t0i*c.x;
      ar1 += t1r*c.x - t1i*c.y; ai1 += t1r*c.y + t1i*c.x;
    }
    int mm = wv*2;
    *(float2*)(CO + (mm*64 + lane)*2)     = make_float2(ar0, ai0);
    *(float2*)(CO + ((mm+1)*64 + lane)*2) = make_float2(ar1, ai1);
  }
  __syncthreads();

  // ---- phase B: mo[m][o] = sum_i coeff[m][i] * W[my][i][o] (complex) ----
  {
    #pragma unroll
    for (int t2=0; t2<2; ++t2){
      int mm = wv*2 + t2;
      int m = mq*8 + mm;
      int blk = m >> 4, mloc = m & 15;
      int my = mloc*16 + y;
      const unsigned* wb = Wt + ((size_t)((l*2+blk)*256 + my))*4096 + lane;
      float mr = 0.f, mi = 0.f;
      for (int i=0;i<64;++i){
        float2 cc = *(const float2*)(CO + (mm*64 + i)*2);
        union { unsigned u; _Float16 h[2]; } pk;
        pk.u = wb[(size_t)i*64];
        float wr_f = (float)pk.h[0], wi_f = (float)pk.h[1];
        mr += cc.x*wr_f - cc.y*wi_f;
        mi += cc.x*wi_f + cc.y*wr_f;
      }
      *(float2*)(MS + (((size_t)(n*16+y)*32 + m)*64 + lane)*2) = make_float2(mr, mi);
    }
  }
}

// ---------------- spectral phase C: idftH, h-quarter per block ----------------
__global__ __launch_bounds__(256) void k_specC(const float* __restrict__ MS,
                                               const float* __restrict__ twB,
                                               float* __restrict__ G){
  __shared__ float SM[32*64*2]; // 16KB
  int bid = blockIdx.x;
  int hq = bid / 160;
  int pid = bid - hq*160;
  int y = pid & 15, n = pid >> 4;
  int tid = threadIdx.x;
  int lane = tid & 63;
  int wv = __builtin_amdgcn_readfirstlane(tid >> 6);

  {
    const float4* src = (const float4*)(MS + ((size_t)(n*16+y)*32)*128);
    float4* dst = (float4*)SM;
    #pragma unroll
    for (int t=0; t<4; ++t) dst[tid + t*256] = src[tid + t*256];
  }
  __syncthreads();

  float f = (y==0) ? (1.f/32768.f) : (2.f/32768.f);
  for (int k=0;k<8;++k){
    int h = hq*32 + wv*8 + k;
    const float* tb = twB + h*64;      // wave-uniform -> s_load
    float gr=0.f, gi=0.f;
    #pragma unroll
    for (int m=0;m<32;++m){
      float tr = tb[m*2], ti = tb[m*2+1];
      float2 mo2 = *(const float2*)(SM + (m*64+lane)*2);
      gr += tr*mo2.x - ti*mo2.y;
      gi += tr*mo2.y + ti*mo2.x;
    }
    size_t gb = (((size_t)(n*128+h)*16 + y)*2)*64 + lane;
    G[gb]      = gr*f;
    G[gb + 64] = gi*f;
  }
}

// ---------------- fused skip-GEMM + inverse DFT-W + gelu (+ next-layer DFT-W / downdim) ----------------
// 512 threads, 8 waves. flags: 1 = emit Cy for next layer; 2 = last layer (fused downdim -> out)
__global__ __launch_bounds__(512, 4) void k_combine_mfma(const _Float16* __restrict__ act_in,
                                                         const float* __restrict__ G,
                                                         const _Float16* __restrict__ Tspec,
                                                         const _Float16* __restrict__ TdftW,
                                                         const float* __restrict__ cw,
                                                         const float* __restrict__ cb,
                                                         const float* __restrict__ wd,
                                                         const float* __restrict__ bd,
                                                         _Float16* __restrict__ act_out,
                                                         float* __restrict__ Cy,
                                                         float* __restrict__ outp,
                                                         int flags){
  __shared__ __align__(16) _Float16 Lh[40960]; // 80 KB total
  _Float16* Bx = Lh;            // [w 256][k 128] chunk-swizzled (fsw_c), 64 KB
  _Float16* At = Lh + 32768;    // [o 64][k 128] chunk-swizzled (o&7), 16 KB
  int tid = threadIdx.x;
  int h = blockIdx.x & 127, n = blockIdx.x >> 7;

  { // act rows -> Bx transposed, pair-packed dword writes
    int rp = tid >> 4, sub = tid & 15;     // 32 row-pairs x 16 w-subranges
    int i0 = 2*rp;
    int wbase = sub*16;
    const _Float16* r0 = act_in + (size_t)(n*64+i0)*32768 + (size_t)h*256 + wbase;
    const _Float16* r1 = r0 + 32768;
    h8 A0 = *(const h8*)r0,     A1 = *(const h8*)(r0+8);
    h8 B0 = *(const h8*)r1,     B1 = *(const h8*)(r1+8);
    int cbs = rp >> 2;        // i0>>3
    int lo  = i0 & 7;         // half-offset within chunk (even)
    #pragma unroll
    for (int k=0;k<16;++k){
      union { _Float16 hh[2]; unsigned u; } pk;
      pk.hh[0] = (k<8) ? A0[k] : A1[k-8];
      pk.hh[1] = (k<8) ? B0[k] : B1[k-8];
      int w = wbase + k;
      int chunk = cbs ^ fsw_c(w);
      *(unsigned*)(Bx + w*128 + chunk*8 + lo) = pk.u;
    }
  }
  { // cw -> At (k 0..63)
    int o = tid >> 3, seg = (tid & 7)*8;
    float4 c0 = *(const float4*)(cw + o*64 + seg);
    float4 c1 = *(const float4*)(cw + o*64 + seg + 4);
    h8 v;
    v[0]=(_Float16)c0.x; v[1]=(_Float16)c0.y; v[2]=(_Float16)c0.z; v[3]=(_Float16)c0.w;
    v[4]=(_Float16)c1.x; v[5]=(_Float16)c1.y; v[6]=(_Float16)c1.z; v[7]=(_Float16)c1.w;
    int ch0 = (seg>>3) ^ (o & 7);
    *(h8*)(At + o*128 + ch0*8) = v;
  }
  { // G -> At (k 64..95)
    const float* gp = G + (size_t)(n*128 + h)*2048 + tid*4;
    float4 g = *(const float4*)gp;
    float gvx[4] = {g.x, g.y, g.z, g.w};
    int idx0 = tid*4;
    int yc = idx0 >> 6;          // uniform over the 4 values
    int o0 = idx0 & 63;
    int kk = 64 + yc;
    #pragma unroll
    for (int j=0;j<4;++j){
      int o = o0 + j;
      int chunk = (kk >> 3) ^ (o & 7);
      At[o*128 + chunk*8 + (kk & 7)] = (_Float16)gvx[j];
    }
  }
  { // Tspec -> Bx (k 64..95)
    int w = tid >> 1, half = tid & 1;
    const _Float16* tp = Tspec + w*32 + half*16;
    #pragma unroll
    for (int c=0;c<2;++c){
      h8 v = *(const h8*)(tp + c*8);
      int cc = half*2 + c;
      int chunk = (8 + cc) ^ fsw_c(w);
      *(h8*)(Bx + w*128 + chunk*8) = v;
    }
  }
  __syncthreads();

  int lane = tid & 63;
  int l31 = lane & 31, l5 = lane >> 5;
  int w0i = tid >> 6;            // 0..7
  int mt = w0i & 1, ng = w0i >> 1;  // o-half, w-quarter-pair
  int o_lane = mt*32 + l31;

  h8 af[6];
  #pragma unroll
  for (int ks=0;ks<6;++ks){
    int kb = ks*16 + l5*8;
    int chunk = (kb>>3) ^ (o_lane & 7);
    af[ks] = *(const h8*)(At + o_lane*128 + chunk*8);
  }
  float bias[16];
  #pragma unroll
  for (int j=0;j<16;++j) bias[j] = cb[mt*32 + (j&3) + 8*(j>>2) + 4*l5];

  f16v acc[2];
  #pragma unroll
  for (int q=0;q<2;++q)
    #pragma unroll
    for (int j=0;j<16;++j) acc[q][j] = bias[j];

  #pragma unroll
  for (int q=0;q<2;++q){
    int w = (ng*2+q)*32 + l31;
    const _Float16* bbase = Bx + w*128;
    int wf = fsw_c(w);
    #pragma unroll
    for (int ks=0;ks<6;++ks){
      int kb = ks*16 + l5*8;
      int chunk = (kb>>3) ^ wf;
      h8 bf = *(const h8*)(bbase + chunk*8);
      acc[q] = __builtin_amdgcn_mfma_f32_32x32x16_f16(af[ks], bf, acc[q], 0,0,0);
    }
  }

  // ---- epilogue: gelu (fp32), optional act store, then fused tail ----
  float gvv[32];
  #pragma unroll
  for (int q=0;q<2;++q)
    #pragma unroll
    for (int j=0;j<16;++j) gvv[q*16+j] = gelu_f(acc[q][j]);

  if (flags != 2){
    #pragma unroll
    for (int q=0;q<2;++q){
      int wcol = (ng*2+q)*32 + l31;
      #pragma unroll
      for (int j=0;j<16;++j){
        int o = mt*32 + (j&3) + 8*(j>>2) + 4*l5;
        act_out[(size_t)(n*64+o)*32768 + (size_t)h*256 + wcol] = (_Float16)gvv[q*16+j];
      }
    }
  }
  __syncthreads();   // all phase-1 LDS reads complete; regions reusable

  if (flags == 1){
    // ---- fused DFT-W for next layer: Cy[y2 32][o 64] = sum_w Td[y2][w] * g[o][w] ----
    _Float16* gL  = Lh;           // [o 64][w 256] chunk-swizzled (o&7), 32 KB
    _Float16* TdL = Lh + 16384;   // [y2 32][w 256] chunk-swizzled (y2&7), 16 KB
    #pragma unroll
    for (int q=0;q<2;++q){
      int wcol = (ng*2+q)*32 + l31;
      int wc3 = wcol >> 3, wc7 = wcol & 7;
      #pragma unroll
      for (int j=0;j<16;++j){
        int o = mt*32 + (j&3) + 8*(j>>2) + 4*l5;
        gL[o*256 + ((wc3 ^ (o & 7))*8) + wc7] = (_Float16)gvv[q*16+j];
      }
    }
    { // TdftW -> TdL
      int y2 = tid & 31, ws = (tid >> 5)*16;
      const _Float16* src = TdftW + y2*256 + ws;
      #pragma unroll
      for (int k=0;k<2;++k){
        h8 v = *(const h8*)(src + k*8);
        int chunk = ((ws>>3)+k) ^ (y2 & 7);
        *(h8*)(TdL + y2*256 + chunk*8) = v;
      }
    }
    __syncthreads();
    float* P = (float*)(Lh + 32768);   // 4 tiles [32 y2][32 o] fp32, 16 KB (At region)
    if (w0i < 4){
      int mt2 = w0i & 1, kh = w0i >> 1;
      int ocol = mt2*32 + l31;
      f16v acc2;
      #pragma unroll
      for (int j=0;j<16;++j) acc2[j] = 0.f;
      #pragma unroll
      for (int ks=0;ks<8;++ks){
        int kb = (kh*8+ks)*16 + l5*8;
        h8 af2 = *(const h8*)(gL  + ocol*256 + (((kb>>3) ^ (ocol & 7))*8));
        h8 bf2 = *(const h8*)(TdL + l31*256  + (((kb>>3) ^ (l31 & 7))*8));
        acc2 = __builtin_amdgcn_mfma_f32_32x32x16_f16(bf2, af2, acc2, 0,0,0);
      }
      #pragma unroll
      for (int j=0;j<16;++j){
        int y2 = (j&3) + 8*(j>>2) + 4*l5;
        P[w0i*1024 + y2*32 + l31] = acc2[j];
      }
    }
    __syncthreads();
    #pragma unroll
    for (int rep=0;rep<2;++rep){
      int t = rep*512 + tid;
      int yy = t >> 6, o = t & 63, mt2 = o >> 5, o31 = o & 31;
      float re = P[mt2*1024 + (2*yy)*32 + o31]   + P[(2+mt2)*1024 + (2*yy)*32 + o31];
      float im = P[mt2*1024 + (2*yy+1)*32 + o31] + P[(2+mt2)*1024 + (2*yy+1)*32 + o31];
      *(float2*)(Cy + (((size_t)(n*16+yy)*128 + h)*64 + o)*2) = make_float2(re, im);
    }
  } else {
    // ---- fused downdim: out[ch] = bd[ch] + sum_o wd[ch][o] * g[o][w] ----
    float p00=0.f,p01=0.f,p10=0.f,p11=0.f;   // [ch][q]
    #pragma unroll
    for (int j=0;j<16;++j){
      int o = mt*32 + (j&3) + 8*(j>>2) + 4*l5;
      float w0d = wd[o], w1d = wd[64+o];
      p00 += w0d*gvv[j];     p10 += w1d*gvv[j];
      p01 += w0d*gvv[16+j];  p11 += w1d*gvv[16+j];
    }
    p00 += __shfl_xor(p00,32); p10 += __shfl_xor(p10,32);
    p01 += __shfl_xor(p01,32); p11 += __shfl_xor(p11,32);
    float* red = (float*)(Lh + 32768);   // [wcol 256][mt 2][ch 2]
    if (l5 == 0){
      int wa = (ng*2+0)*32 + l31, wb2 = (ng*2+1)*32 + l31;
      red[wa*4  + mt*2 + 0] = p00; red[wa*4  + mt*2 + 1] = p10;
      red[wb2*4 + mt*2 + 0] = p01; red[wb2*4 + mt*2 + 1] = p11;
    }
    __syncthreads();
    {
      int ch = tid >> 8, wcol = tid & 255;
      float v = red[wcol*4 + ch] + red[wcol*4 + 2 + ch] + bd[ch];
      outp[(size_t)n*65536 + (size_t)ch*32768 + (size_t)h*256 + wcol] = v;
    }
  }
}

extern "C" void kernel_launch(void* const* d_in, const int* in_sizes, int n_in,
                              void* d_out, int out_size, void* d_ws, size_t ws_size,
                              hipStream_t stream) {
  const float* sv  = (const float*)d_in[0];
  const float* upw = (const float*)d_in[1];
  const float* upb = (const float*)d_in[2];
  const float* smw = (const float*)d_in[3];
  const float* smb = (const float*)d_in[4];
  const float* fwr = (const float*)d_in[5];
  const float* fwi = (const float*)d_in[6];
  const float* fcw = (const float*)d_in[7];
  const float* fcb = (const float*)d_in[8];
  const float* ddw = (const float*)d_in[9];
  const float* ddb = (const float*)d_in[10];
  float* out = (float*)d_out;
  (void)smb; // spatially uniform per (n,o); cancelled exactly by instance-norm mean subtraction

  float* W = (float*)d_ws;
  _Float16* actA = (_Float16*)W;                    // 20971520 halves
  _Float16* actB = (_Float16*)(W + 10485760);       // 20971520 halves
  float* Cy    = W + 20971520;                      // 2621440  [n][y][h][e][2]
  float* G     = W + 23592960;                      // 2621440  [n][h][y][c][o]
  float* part  = W + 26214400;                      // Rpart/Bnd/MS
  float* stats = W + 28180480;                      // 1280
  float* Keff  = W + 28181760;                      // 4096
  float* twFwH = W + 28185856;                      // 8192
  float* twBwH = W + 28194048;                      // 8192
  _Float16* Tspec = (_Float16*)(W + 28202240);      // 8192 halves
  _Float16* TdftW = (_Float16*)(W + 28206336);      // 8192 halves
  unsigned* Wt   = (unsigned*)(W + 28210432);       // 8388608 u32 (33.5 MB)

  float* Rpart = part;          // 23040 floats: [n 10][band 32][pair 8][lag 9]
  float* Bnd   = part + 30000;  // 1440 floats:  [n 10][144]
  float* MS    = part + 65536;  // 655360 floats: [n 10][y 16][m 32][o 64][c 2]

  k_tables_fold<<<100,256,0,stream>>>(twFwH, twBwH, Tspec, TdftW, smw, upw, upb, Keff);
  k_transW<<<512,256,0,stream>>>(fwr, fwi, Wt);
  k_corrbnd<<<330,512,0,stream>>>(sv, Rpart, Bnd);
  k_stats3<<<10,256,0,stream>>>(Rpart, Bnd, Keff, stats);
  k_convnorm<<<1280,256,0,stream>>>(sv, Keff, stats, actA);
  k_dftW_mfma<<<640,256,0,stream>>>(actA, TdftW, Cy);

  _Float16* xa = actA; _Float16* xb = actB;
  for (int l=0;l<4;++l){
    k_specAB<<<640,256,0,stream>>>(Cy, twFwH, Wt, MS, l);
    k_specC<<<640,256,0,stream>>>(MS, twBwH, G);
    k_combine_mfma<<<1280,512,0,stream>>>(xa, G, Tspec, TdftW,
                                          fcw + (size_t)l*4096, fcb + (size_t)l*64,
                                          ddw, ddb, xb, Cy, out, (l<3)?1:2);
    _Float16* t = xa; xa = xb; xb = t;
  }
}